// Round 15
// baseline (176.392 us; speedup 1.0000x reference)
//
#include <hip/hip_runtime.h>
#include <hip/hip_bf16.h>

#define BB 4
#define TT 2048
#define CC 1024
#define HH 16
#define HD 64
#define NQ (3*CC)
// 1/sqrt(64) * log2(e): attention done in exp2 domain
#define QSCALE 0.18033688011112042f

typedef __attribute__((ext_vector_type(8))) short bf16x8;
typedef __attribute__((ext_vector_type(4))) short short4_t;
typedef __attribute__((ext_vector_type(4))) float f32x4;

#define MFMA(a,b,c) __builtin_amdgcn_mfma_f32_16x16x32_bf16(a,b,c,0,0,0)

// async global->LDS, 16B per lane; LDS dest is wave-uniform base + lane*16
#define ASYNC16(gsrc, ldst) \
  __builtin_amdgcn_global_load_lds((const __attribute__((address_space(1))) void*)(gsrc), \
                                   (__attribute__((address_space(3))) void*)(ldst), 16, 0, 0)

// row-swizzle for 64-short-stride LDS tiles (16B-chunk granularity)
#define SWZA(row) (((((row) & 7) + (((row) >> 3) & 3)) & 7) << 3)

static __device__ __forceinline__ short f2bf(float f){
    union { float f; unsigned u; } v; v.f = f;
    unsigned r = v.u + 0x7FFFu + ((v.u >> 16) & 1u);   // RNE
    return (short)(r >> 16);
}
// packed f32x2 -> bf16x2 (RNE), single HW instruction
static __device__ __forceinline__ unsigned cvtpk(float a, float b){
    unsigned r;
    asm("v_cvt_pk_bf16_f32 %0, %1, %2" : "=v"(r) : "v"(a), "v"(b));
    return r;
}

// ---------------- prepass: x fp32 -> bf16 (row-major, unchanged layout)
__global__ __launch_bounds__(256)
void convert_x(const float* __restrict__ x, short* __restrict__ xb)
{
    int i = (blockIdx.x * 256 + threadIdx.x) * 8;
    float4 a = *reinterpret_cast<const float4*>(&x[i]);
    float4 b = *reinterpret_cast<const float4*>(&x[i+4]);
    bf16x8 o = { f2bf(a.x), f2bf(a.y), f2bf(a.z), f2bf(a.w),
                 f2bf(b.x), f2bf(b.y), f2bf(b.z), f2bf(b.w) };
    *reinterpret_cast<bf16x8*>(&xb[i]) = o;
}

// ---------------- prepass: w fp32 [K=1024][N] -> wT bf16 [N][1024]
__global__ __launch_bounds__(256)
void transpose_w(const float* __restrict__ w, short* __restrict__ wT, int N)
{
    __shared__ short sm[64*72];
    const int kt0 = blockIdx.x * 64;
    const int nt0 = blockIdx.y * 64;
    const int t = threadIdx.x;
    const int r  = t >> 4;
    const int c4 = (t & 15) * 4;
#pragma unroll
    for (int it = 0; it < 4; it++){
        int k = r + it*16;
        float4 v = *reinterpret_cast<const float4*>(&w[(size_t)(kt0 + k)*N + nt0 + c4]);
        sm[(c4+0)*72 + k] = f2bf(v.x);
        sm[(c4+1)*72 + k] = f2bf(v.y);
        sm[(c4+2)*72 + k] = f2bf(v.z);
        sm[(c4+3)*72 + k] = f2bf(v.w);
    }
    __syncthreads();
    const int nl = t >> 2;
    const int kc = (t & 3) * 16;
    bf16x8 o0 = *reinterpret_cast<const bf16x8*>(&sm[nl*72 + kc]);
    bf16x8 o1 = *reinterpret_cast<const bf16x8*>(&sm[nl*72 + kc + 8]);
    short* dst = &wT[(size_t)(nt0 + nl)*CC + kt0 + kc];
    *reinterpret_cast<bf16x8*>(dst)     = o0;
    *reinterpret_cast<bf16x8*>(dst + 8) = o1;
}

// ---------------- QKV GEMM v3: 128x256 tile, BK=32, 4-slot LDS ring (96KB),
// counted vmcnt(6) pipeline (never drained in main loop), 512 threads / 8 waves,
// grid 768 = exactly 3 rounds on 256 CUs (no tail idle).
// q/k scattered to [B,H,T,HD]; v written transposed to vtb [B,H,HD,T].

#define QKV_STAGE(s) do{                                                     \
    short* ab_ = ring + (s)*4096;                                            \
    ASYNC16(pA0, ab_ + ldsWA);                                               \
    short* bb_ = ring + 16384 + (s)*8192;                                    \
    ASYNC16(pB0, bb_ + ldsWA); ASYNC16(pB1, bb_ + ldsWB1);                   \
    pA0 += 32; pB0 += 32; pB1 += 32; }while(0)

#define QKV_COMPUTE(s) do{                                                   \
    const short* baseA_ = ring + (s)*4096;                                   \
    const short* baseB_ = ring + 16384 + (s)*8192;                           \
    bf16x8 a_[4], b_[4];                                                     \
    _Pragma("unroll") for(int m_=0;m_<4;m_++)                                \
        a_[m_] = *reinterpret_cast<const bf16x8*>(baseA_ + aOff[m_]);        \
    _Pragma("unroll") for(int n_=0;n_<4;n_++)                                \
        b_[n_] = *reinterpret_cast<const bf16x8*>(baseB_ + bOff[n_]);        \
    __builtin_amdgcn_s_setprio(1);                                           \
    _Pragma("unroll") for(int m_=0;m_<4;m_++)                                \
      _Pragma("unroll") for(int n_=0;n_<4;n_++)                              \
        acc[m_][n_] = MFMA(a_[m_], b_[n_], acc[m_][n_]);                     \
    __builtin_amdgcn_s_setprio(0); }while(0)

#define QKV_SYNC(N) do{                                                      \
    asm volatile("s_waitcnt vmcnt(" #N ")" ::: "memory");                    \
    __builtin_amdgcn_s_barrier();                                            \
    __builtin_amdgcn_sched_barrier(0); }while(0)

__global__ __launch_bounds__(512, 2)
void qkv_gemm(const short* __restrict__ xb, const short* __restrict__ wT,
              const float* __restrict__ bias,
              short* __restrict__ qb, short* __restrict__ kb, short* __restrict__ vtb)
{
    __shared__ short ring[49152];       // 96KB: A slots [0,16384), B slots [16384,49152)
    const int bid = blockIdx.x;
    const int swz = (bid & 7) * 96 + (bid >> 3);    // 768 blocks, bijective XCD swizzle
    const int bm = swz / 12, bn = swz % 12;
    const int m0 = bm*128, n0 = bn*256;
    const int t  = threadIdx.x;
    const int wid = t >> 6, lane = t & 63;
    const int wr = wid >> 2, wc = wid & 3;          // 2M x 4N wave grid; per-wave 64x64
    const int l15 = lane & 15, lh = lane >> 4;

    // staging maps: A covers u = t (128 rows x 4 chunks); B: u0 = t, u1 = 512+t (256 rows)
    int arow, acol, brow0, bcol0, brow1, bcol1;
    { int u = t;       arow  = u >> 2; int c = u & 3; acol  = c ^ ((arow  >> 1) & 3); }
    { int u = t;       brow0 = u >> 2; int c = u & 3; bcol0 = c ^ ((brow0 >> 1) & 3); }
    { int u = 512 + t; brow1 = u >> 2; int c = u & 3; bcol1 = c ^ ((brow1 >> 1) & 3); }
    const short* pA0 = xb + (size_t)(m0+arow)*CC  + acol*8;
    const short* pB0 = wT + (size_t)(n0+brow0)*CC + bcol0*8;
    const short* pB1 = wT + (size_t)(n0+brow1)*CC + bcol1*8;
    const int ldsWA  = wid*512;                     // shorts, within slot (issue 0)
    const int ldsWB1 = 4096 + wid*512;              // B issue 1

    // fragment read offsets (shorts, relative to slot bases)
    int aOff[4], bOff[4];
#pragma unroll
    for (int m=0;m<4;m++){
        int row = wr*64 + m*16 + l15;
        aOff[m] = row*32 + (lh ^ ((row>>1)&3))*8;
    }
#pragma unroll
    for (int n=0;n<4;n++){
        int row = wc*64 + n*16 + l15;
        bOff[n] = row*32 + (lh ^ ((row>>1)&3))*8;
    }

    f32x4 acc[4][4];
#pragma unroll
    for (int m=0;m<4;m++)
#pragma unroll
      for (int n=0;n<4;n++) acc[m][n] = (f32x4)0.f;

    // prologue: stage subtiles 0,1,2 (9 loads in flight); wait for subtile 0
    QKV_STAGE(0); QKV_STAGE(1); QKV_STAGE(2);
    QKV_SYNC(6);

    // main loop: kt = 0..27 (stage kt+3, compute kt, keep 6 loads in flight)
    for (int blk = 0; blk < 7; blk++){
#pragma unroll
        for (int j = 0; j < 4; j++){
            QKV_STAGE((j+3)&3);
            QKV_COMPUTE(j);
            QKV_SYNC(6);
        }
    }
    // peeled tail: kt = 28 (stage 31), 29, 30, 31
    QKV_STAGE(3); QKV_COMPUTE(0); QKV_SYNC(6);
    QKV_COMPUTE(1);               QKV_SYNC(3);
    QKV_COMPUTE(2);               QKV_SYNC(0);
    QKV_COMPUTE(3);
    __syncthreads();                                 // ring is dead; reuse for V-transpose

    if (n0 < 2*CC) {
        // q/k epilogue: scatter [B,H,T,HD]; fold exp2-domain scale into q
#pragma unroll
        for (int n=0;n<4;n++){
            int col = n0 + wc*64 + n*16 + l15;
            int sect = col >> 10;
            int cc = col & 1023;
            int h = cc >> 6, d = cc & 63;
            float bv = bias[col];
            short* dst = (sect==0) ? qb : kb;
            float mul = (sect==0) ? QSCALE : 1.f;
#pragma unroll
            for (int m=0;m<4;m++)
#pragma unroll
              for (int r=0;r<4;r++){
                int row = m0 + wr*64 + m*16 + lh*4 + r;
                int b_ = row >> 11, tt_ = row & (TT-1);
                float v = (acc[m][n][r] + bv) * mul;
                dst[((size_t)(b_*HH + h)*TT + tt_)*HD + d] = f2bf(v);
              }
        }
    } else {
        // v epilogue: transpose 128x256 tile via ring-LDS -> vtb [bh][d][T] coalesced
        const int b_ = m0 >> 11, t0 = m0 & (TT-1);
        short* Ts = ring;                            // [256 cols][136]
#pragma unroll
        for (int n=0;n<4;n++){
            int colL = wc*64 + n*16 + l15;           // 0..255
            float bv = bias[n0 + colL];
#pragma unroll
            for (int m=0;m<4;m++){
                int rowL = wr*64 + m*16 + lh*4;
                short4_t pk = { f2bf(acc[m][n][0]+bv), f2bf(acc[m][n][1]+bv),
                                f2bf(acc[m][n][2]+bv), f2bf(acc[m][n][3]+bv) };
                *reinterpret_cast<short4_t*>(&Ts[colL*136 + rowL]) = pk;
            }
        }
        __syncthreads();
        {
            int c = t >> 1;                          // 0..255
            int vcol = n0 - 2*CC + c;
            short* dst = vtb + ((size_t)(b_*HH + (vcol>>6))*HD + (vcol&63))*TT + t0;
#pragma unroll
            for (int it=0; it<8; it++){
                int r0 = (t&1)*8 + it*16;
                *reinterpret_cast<bf16x8*>(&dst[r0]) =
                    *reinterpret_cast<const bf16x8*>(&Ts[c*136 + r0]);
            }
        }
    }
}

// ---------------- Flash attention (R11 config): unpaired 128-row q-tiles,
// swapped QK^T, K/V via global_load_lds, hoisted LDS offsets, 3 blocks/CU.
__global__ __launch_bounds__(256, 3)
void attn_kernel(const short* __restrict__ qb, const short* __restrict__ kb,
                 const short* __restrict__ vtb, short* __restrict__ yb)
{
    __shared__ short Ks[2][64*64];   // [kv][d] bf16, SWZA chunk swizzle
    __shared__ short Vt[2][64*64];   // [d][kv] bf16, SWZA chunk swizzle
    __shared__ short Ps[4][32*64];   // per-wave P [qloc][kv] bf16, SWZA

    const int bh = blockIdx.x;            // 0..63 : id%8==bh%8 -> same-head blocks share XCD
    const int qt = 15 - blockIdx.y;       // descending: longest blocks dispatch first
    const int b_ = bh >> 4, h = bh & 15;
    const short* qp  = qb  + (size_t)bh*TT*HD;
    const short* kp  = kb  + (size_t)bh*TT*HD;
    const short* vtp = vtb + (size_t)bh*HD*TT;   // [d][T]
    const int t = threadIdx.x, wid = t >> 6, lane = t & 63;
    const int l15 = lane & 15, lh = lane >> 4;

    // ---- hoisted LDS byte offsets (static-indexed arrays -> register-resident)
    int kvoffB[8];   // [ks*4+i] : K-frag / V-frag / P-read offsets
#pragma unroll
    for (int ks=0;ks<2;ks++)
#pragma unroll
      for (int i=0;i<4;i++){
        int row = i*16 + l15;
        kvoffB[ks*4+i] = ((row*64 + ks*32 + lh*8) ^ SWZA(row)) * 2;
      }
    int pwB[8];      // [m*4+f] : P-write offsets (uint2)
#pragma unroll
    for (int m=0;m<2;m++){
        int qloc = m*16 + l15;
#pragma unroll
        for (int f=0;f<4;f++)
            pwB[m*4+f] = ((qloc*64 + f*16 + lh*4) ^ SWZA(qloc)) * 2;
    }
    char* KsB = (char*)&Ks[0][0];
    char* VtB = (char*)&Vt[0][0];
    char* PsB = (char*)&Ps[wid][0];

    // staging map: u = (wid*2+i)*64 + lane; row = u>>3, chunk = u&7 (16B chunks)
    const int su0 = (wid*2+0)*64 + lane;
    const int su1 = (wid*2+1)*64 + lane;
    const int sr0 = su0 >> 3, sc0 = (su0 & 7) ^ (SWZA(su0 >> 3) >> 3);
    const int sr1 = su1 >> 3, sc1 = (su1 & 7) ^ (SWZA(su1 >> 3) >> 3);

    // running global pointers (advance after each staged tile)
    const short* kg0 = kp  + (size_t)sr0*HD + sc0*8;
    const short* kg1 = kp  + (size_t)sr1*HD + sc1*8;
    const short* vg0 = vtp + (size_t)sr0*TT + sc0*8;
    const short* vg1 = vtp + (size_t)sr1*TT + sc1*8;

    const bf16x8 ones = { 0x3F80,0x3F80,0x3F80,0x3F80,0x3F80,0x3F80,0x3F80,0x3F80 };

    auto stageN = [&](int buf){
        ASYNC16(kg0, &Ks[buf][(wid*2+0)*512]);
        ASYNC16(kg1, &Ks[buf][(wid*2+1)*512]);
        ASYNC16(vg0, &Vt[buf][(wid*2+0)*512]);
        ASYNC16(vg1, &Vt[buf][(wid*2+1)*512]);
        kg0 += 64*HD; kg1 += 64*HD; vg0 += 64; vg1 += 64;
    };

    const int wq0 = qt*128 + wid*32;      // this wave's first q row

    bf16x8 qf[2][2];
#pragma unroll
    for (int m=0;m<2;m++)
#pragma unroll
      for (int ks=0;ks<2;ks++)
        qf[m][ks] = *reinterpret_cast<const bf16x8*>(
            &qp[(size_t)(wq0 + m*16 + l15)*HD + ks*32 + lh*8]);

    f32x4 po[2][4];
    f32x4 pden[2];
#pragma unroll
    for (int m=0;m<2;m++){
        pden[m] = (f32x4)0.f;
#pragma unroll
        for (int n=0;n<4;n++) po[m][n] = (f32x4)0.f;
    }

    const int ntk = 2*(qt + 1);           // always even

    stageN(0);
    __syncthreads();   // implicit vmcnt(0) drain before barrier

    for (int kt = 0; kt < ntk; ){
#pragma unroll
        for (int cur = 0; cur < 2; cur++, kt++){    // cur is compile-time after unroll
            const int kv0 = kt*64;
            if (kt+1 < ntk) stageN(cur ^ 1);        // fly during compute

            if (kv0 <= wq0 + 31){     // wave-uniform causal activity test
                // S^T = K Q^T : per lane q = l15 (const), kv = f*16 + lh*4 + r
                f32x4 s[2][4];
#pragma unroll
                for (int m=0;m<2;m++)
#pragma unroll
                  for (int f=0;f<4;f++) s[m][f] = (f32x4)0.f;
                __builtin_amdgcn_s_setprio(1);
#pragma unroll
                for (int ks=0;ks<2;ks++){
#pragma unroll
                    for (int f=0;f<4;f++){
                        bf16x8 kf = *reinterpret_cast<const bf16x8*>(
                            KsB + cur*8192 + kvoffB[ks*4+f]);
                        s[0][f] = MFMA(kf, qf[0][ks], s[0][f]);
                        s[1][f] = MFMA(kf, qf[1][ks], s[1][f]);
                    }
                }
                __builtin_amdgcn_s_setprio(0);
                // causal mask (straddling tiles only): q is per-lane scalar
#pragma unroll
                for (int m=0;m<2;m++){
                    if (kv0 + 63 > wq0 + m*16){
                        int qm = wq0 + m*16 + l15;
#pragma unroll
                        for (int f=0;f<4;f++)
#pragma unroll
                          for (int r=0;r<4;r++){
                            int kv = kv0 + f*16 + lh*4 + r;
                            if (kv > qm) s[m][f][r] = -1e30f;
                          }
                    }
                }
                // P = exp2(S'); pack via v_cvt_pk_bf16_f32; one b64 LDS write per f
#pragma unroll
                for (int m=0;m<2;m++){
#pragma unroll
                    for (int f=0;f<4;f++){
                        uint2 pk;
                        pk.x = cvtpk(exp2f(s[m][f][0]), exp2f(s[m][f][1]));
                        pk.y = cvtpk(exp2f(s[m][f][2]), exp2f(s[m][f][3]));
                        *reinterpret_cast<uint2*>(PsB + pwB[m*4+f]) = pk;
                    }
                }
                // O += P V ; den += P * 1  (ones-column via constant B-fragment)
                __builtin_amdgcn_s_setprio(1);
#pragma unroll
                for (int k2=0;k2<2;k2++){
                    bf16x8 pa[2];
#pragma unroll
                    for (int m=0;m<2;m++)
                        pa[m] = *reinterpret_cast<const bf16x8*>(PsB + kvoffB[k2*4+m]);
                    pden[0] = MFMA(pa[0], ones, pden[0]);
                    pden[1] = MFMA(pa[1], ones, pden[1]);
#pragma unroll
                    for (int n=0;n<4;n++){
                        bf16x8 vf = *reinterpret_cast<const bf16x8*>(
                            VtB + cur*8192 + kvoffB[k2*4+n]);
                        po[0][n] = MFMA(pa[0], vf, po[0][n]);
                        po[1][n] = MFMA(pa[1], vf, po[1][n]);
                    }
                }
                __builtin_amdgcn_s_setprio(0);
            }

            __syncthreads();   // drains staged loads (vmcnt) + publishes next buffer
        }
    }

    // epilogue -> y [B,T,C] bf16
#pragma unroll
    for (int m=0;m<2;m++){
        float rcp[4];
#pragma unroll
        for (int r=0;r<4;r++) rcp[r] = 1.f / pden[m][r];
#pragma unroll
        for (int n=0;n<4;n++)
#pragma unroll
          for (int r=0;r<4;r++){
            int q = wq0 + m*16 + lh*4 + r;
            int dd = n*16 + l15;
            yb[(size_t)(b_*TT + q)*CC + h*HD + dd] = f2bf(po[m][n][r] * rcp[r]);
          }
    }
}

// ---------------- Output projection (bf16): y [8192,1024] @ wpT^T + bias -> fp32 out
__global__ __launch_bounds__(256, 2)
void proj_gemm(const short* __restrict__ y, const short* __restrict__ wpT,
               const float* __restrict__ bias, float* __restrict__ out)
{
    __shared__ short As[128*64];
    __shared__ short Bs[128*64];
    const int bid = blockIdx.x;
    const int swz = (bid & 7) * 64 + (bid >> 3);   // 512 blocks
    const int bm = swz >> 3, bn = swz & 7;
    const int m0 = bm*128, n0 = bn*128;
    const int t  = threadIdx.x;
    const int wid = t >> 6, lane = t & 63;
    const int wr = wid >> 1, wc = wid & 1;
    const int l15 = lane & 15, lh = lane >> 4;

    f32x4 acc[4][4];
#pragma unroll
    for (int i=0;i<4;i++)
#pragma unroll
      for (int j=0;j<4;j++) acc[i][j] = (f32x4)0.f;

    for (int k0 = 0; k0 < CC; k0 += 64) {
        __syncthreads();
#pragma unroll
        for (int i=0;i<4;i++){
            int u   = (wid*4 + i)*64 + lane;
            int row = u >> 3, c = u & 7;
            int cs  = c ^ (row & 7);
            ASYNC16(&y[(size_t)(m0+row)*CC + k0 + cs*8],   &As[(wid*4+i)*512]);
            ASYNC16(&wpT[(size_t)(n0+row)*CC + k0 + cs*8], &Bs[(wid*4+i)*512]);
        }
        __syncthreads();
#pragma unroll
        for (int ks=0;ks<2;ks++){
            bf16x8 a[4], b[4];
#pragma unroll
            for (int m=0;m<4;m++){
                int row = wr*64 + m*16 + l15;
                a[m] = *reinterpret_cast<const bf16x8*>(&As[row*64 + (((ks<<2)|lh) ^ (row&7))*8]);
            }
#pragma unroll
            for (int n=0;n<4;n++){
                int col = wc*64 + n*16 + l15;
                b[n] = *reinterpret_cast<const bf16x8*>(&Bs[col*64 + (((ks<<2)|lh) ^ (col&7))*8]);
            }
#pragma unroll
            for (int m=0;m<4;m++)
#pragma unroll
              for (int n=0;n<4;n++)
                acc[m][n] = MFMA(a[m], b[n], acc[m][n]);
        }
    }

#pragma unroll
    for (int n=0;n<4;n++){
        int col = n0 + wc*64 + n*16 + l15;
        float bv = bias[col];
#pragma unroll
        for (int m=0;m<4;m++)
#pragma unroll
          for (int r=0;r<4;r++){
            int row = m0 + wr*64 + m*16 + lh*4 + r;
            out[(size_t)row*CC + col] = acc[m][n][r] + bv;
          }
    }
}

extern "C" void kernel_launch(void* const* d_in, const int* in_sizes, int n_in,
                              void* d_out, int out_size, void* d_ws, size_t ws_size,
                              hipStream_t stream) {
    const float* x      = (const float*)d_in[0];
    const float* w_attn = (const float*)d_in[1];
    const float* b_attn = (const float*)d_in[2];
    const float* w_proj = (const float*)d_in[3];
    const float* b_proj = (const float*)d_in[4];
    float* out = (float*)d_out;

    const size_t S = (size_t)BB*TT*CC;   // 8.4M elems
    short* qb  = (short*)d_ws;           // bf16 [B,H,T,HD]
    short* kb  = qb + S;
    short* vtb = kb + S;                 // bf16 [B,H,HD,T]  (V written transposed by qkv)
    short* yx  = vtb + S;                // x-bf16 during prepass+qkv; y-bf16 after attn
    short* wT  = yx + S;                 // bf16 [3072][1024]
    short* wpT = wT + (size_t)NQ*CC;     // bf16 [1024][1024]

    convert_x<<<dim3(S/(256*8)), 256, 0, stream>>>(x, yx);
    transpose_w<<<dim3(CC/64, NQ/64), 256, 0, stream>>>(w_attn, wT, NQ);
    transpose_w<<<dim3(CC/64, CC/64), 256, 0, stream>>>(w_proj, wpT, CC);
    qkv_gemm<<<dim3(768), 512, 0, stream>>>(yx, wT, b_attn, qb, kb, vtb);
    attn_kernel<<<dim3(BB*HH, TT/128), 256, 0, stream>>>(qb, kb, vtb, yx);
    proj_gemm<<<dim3((BB*TT/128)*(CC/128)), 256, 0, stream>>>(yx, wpT, b_proj, out);
}

// Round 16
// 170.769 us; speedup vs baseline: 1.0329x; 1.0329x over previous
//
#include <hip/hip_runtime.h>
#include <hip/hip_bf16.h>

#define BB 4
#define TT 2048
#define CC 1024
#define HH 16
#define HD 64
#define NQ (3*CC)
// 1/sqrt(64) * log2(e): attention done in exp2 domain
#define QSCALE 0.18033688011112042f

typedef __attribute__((ext_vector_type(8))) short bf16x8;
typedef __attribute__((ext_vector_type(4))) short short4_t;
typedef __attribute__((ext_vector_type(4))) float f32x4;

#define MFMA(a,b,c) __builtin_amdgcn_mfma_f32_16x16x32_bf16(a,b,c,0,0,0)

// async global->LDS, 16B per lane; LDS dest is wave-uniform base + lane*16
#define ASYNC16(gsrc, ldst) \
  __builtin_amdgcn_global_load_lds((const __attribute__((address_space(1))) void*)(gsrc), \
                                   (__attribute__((address_space(3))) void*)(ldst), 16, 0, 0)

// row-swizzle for 64-short-stride LDS tiles (16B-chunk granularity)
#define SWZA(row) (((((row) & 7) + (((row) >> 3) & 3)) & 7) << 3)

static __device__ __forceinline__ short f2bf(float f){
    union { float f; unsigned u; } v; v.f = f;
    unsigned r = v.u + 0x7FFFu + ((v.u >> 16) & 1u);   // RNE
    return (short)(r >> 16);
}
// packed f32x2 -> bf16x2 (RNE), single HW instruction
static __device__ __forceinline__ unsigned cvtpk(float a, float b){
    unsigned r;
    asm("v_cvt_pk_bf16_f32 %0, %1, %2" : "=v"(r) : "v"(a), "v"(b));
    return r;
}

// ---------------- prepass: x fp32 -> bf16 (row-major, unchanged layout)
__global__ __launch_bounds__(256)
void convert_x(const float* __restrict__ x, short* __restrict__ xb)
{
    int i = (blockIdx.x * 256 + threadIdx.x) * 8;
    float4 a = *reinterpret_cast<const float4*>(&x[i]);
    float4 b = *reinterpret_cast<const float4*>(&x[i+4]);
    bf16x8 o = { f2bf(a.x), f2bf(a.y), f2bf(a.z), f2bf(a.w),
                 f2bf(b.x), f2bf(b.y), f2bf(b.z), f2bf(b.w) };
    *reinterpret_cast<bf16x8*>(&xb[i]) = o;
}

// ---------------- prepass: w fp32 [K=1024][N] -> wT bf16 [N][1024]
__global__ __launch_bounds__(256)
void transpose_w(const float* __restrict__ w, short* __restrict__ wT, int N)
{
    __shared__ short sm[64*72];
    const int kt0 = blockIdx.x * 64;
    const int nt0 = blockIdx.y * 64;
    const int t = threadIdx.x;
    const int r  = t >> 4;
    const int c4 = (t & 15) * 4;
#pragma unroll
    for (int it = 0; it < 4; it++){
        int k = r + it*16;
        float4 v = *reinterpret_cast<const float4*>(&w[(size_t)(kt0 + k)*N + nt0 + c4]);
        sm[(c4+0)*72 + k] = f2bf(v.x);
        sm[(c4+1)*72 + k] = f2bf(v.y);
        sm[(c4+2)*72 + k] = f2bf(v.z);
        sm[(c4+3)*72 + k] = f2bf(v.w);
    }
    __syncthreads();
    const int nl = t >> 2;
    const int kc = (t & 3) * 16;
    bf16x8 o0 = *reinterpret_cast<const bf16x8*>(&sm[nl*72 + kc]);
    bf16x8 o1 = *reinterpret_cast<const bf16x8*>(&sm[nl*72 + kc + 8]);
    short* dst = &wT[(size_t)(nt0 + nl)*CC + kt0 + kc];
    *reinterpret_cast<bf16x8*>(dst)     = o0;
    *reinterpret_cast<bf16x8*>(dst + 8) = o1;
}

// ---------------- QKV GEMM (bf16): xb [8192,1024] @ wT^T -> q/k bf16 [B,H,T,HD],
// v written TRANSPOSED to vtb [B,H,HD,T] via LDS bounce (v-blocks: bn 16..23).
__global__ __launch_bounds__(256, 2)
void qkv_gemm(const short* __restrict__ xb, const short* __restrict__ wT,
              const float* __restrict__ bias,
              short* __restrict__ qb, short* __restrict__ kb, short* __restrict__ vtb)
{
    __shared__ short smem[128*136];      // As+Bs (16384) and epilogue Ts (17408)
    short* As = smem;                    // [128*64]
    short* Bs = smem + 8192;             // [128*64]
    const int bid = blockIdx.x;
    const int swz = (bid & 7) * 192 + (bid >> 3);   // 1536 blocks, bijective XCD swizzle
    const int bm = swz / (NQ/128);
    const int bn = swz % (NQ/128);
    const int m0 = bm*128, n0 = bn*128;
    const int t  = threadIdx.x;
    const int wid = t >> 6, lane = t & 63;
    const int wr = wid >> 1, wc = wid & 1;
    const int l15 = lane & 15, lh = lane >> 4;

    f32x4 acc[4][4];
#pragma unroll
    for (int i=0;i<4;i++)
#pragma unroll
      for (int j=0;j<4;j++) acc[i][j] = (f32x4)0.f;

    for (int k0 = 0; k0 < CC; k0 += 64) {
        __syncthreads();
#pragma unroll
        for (int i=0;i<4;i++){
            int u   = (wid*4 + i)*64 + lane;
            int row = u >> 3, c = u & 7;
            int cs  = c ^ (row & 7);      // inverse-swizzled source chunk
            ASYNC16(&xb[(size_t)(m0+row)*CC + k0 + cs*8], &As[(wid*4+i)*512]);
            ASYNC16(&wT[(size_t)(n0+row)*CC + k0 + cs*8], &Bs[(wid*4+i)*512]);
        }
        __syncthreads();
#pragma unroll
        for (int ks=0;ks<2;ks++){
            bf16x8 a[4], b[4];
#pragma unroll
            for (int m=0;m<4;m++){
                int row = wr*64 + m*16 + l15;
                a[m] = *reinterpret_cast<const bf16x8*>(&As[row*64 + (((ks<<2)|lh) ^ (row&7))*8]);
            }
#pragma unroll
            for (int n=0;n<4;n++){
                int col = wc*64 + n*16 + l15;
                b[n] = *reinterpret_cast<const bf16x8*>(&Bs[col*64 + (((ks<<2)|lh) ^ (col&7))*8]);
            }
#pragma unroll
            for (int m=0;m<4;m++)
#pragma unroll
              for (int n=0;n<4;n++)
                acc[m][n] = MFMA(a[m], b[n], acc[m][n]);
        }
    }

    if (n0 < 2*CC) {
        // q/k epilogue: scatter [B,H,T,HD]; fold exp2-domain scale into q
#pragma unroll
        for (int n=0;n<4;n++){
            int col = n0 + wc*64 + n*16 + l15;
            int sect = col >> 10;
            int cc = col & 1023;
            int h = cc >> 6, d = cc & 63;
            float bv = bias[col];
            short* dst = (sect==0) ? qb : kb;
            float mul = (sect==0) ? QSCALE : 1.f;
#pragma unroll
            for (int m=0;m<4;m++)
#pragma unroll
              for (int r=0;r<4;r++){
                int row = m0 + wr*64 + m*16 + lh*4 + r;
                int b_ = row >> 11, tt_ = row & (TT-1);
                float v = (acc[m][n][r] + bv) * mul;
                dst[((size_t)(b_*HH + h)*TT + tt_)*HD + d] = f2bf(v);
              }
        }
    } else {
        // v epilogue: transpose 128x128 tile via LDS -> vtb [bh][d][T] coalesced
        __syncthreads();                 // all waves done reading As/Bs
        short* Ts = smem;                // [128 cols][136]
#pragma unroll
        for (int n=0;n<4;n++){
            int colL = wc*64 + n*16 + l15;
            float bv = bias[n0 + colL];
#pragma unroll
            for (int m=0;m<4;m++){
                int rowL = wr*64 + m*16 + lh*4;
                short4_t pk = { f2bf(acc[m][n][0]+bv), f2bf(acc[m][n][1]+bv),
                                f2bf(acc[m][n][2]+bv), f2bf(acc[m][n][3]+bv) };
                *reinterpret_cast<short4_t*>(&Ts[colL*136 + rowL]) = pk;
            }
        }
        __syncthreads();
        const int b_ = m0 >> 11, t0 = m0 & (TT-1);
        const int cc0 = n0 - 2*CC;
#pragma unroll
        for (int pass=0;pass<2;pass++){
            int c = (t >> 2) + pass*64;
            int vcol = cc0 + c;
            short* dst = vtb + ((size_t)(b_*HH + (vcol>>6))*HD + (vcol&63))*TT + t0;
#pragma unroll
            for (int it=0;it<4;it++){
                int r0 = (t & 3)*8 + it*32;
                *reinterpret_cast<bf16x8*>(&dst[r0]) =
                    *reinterpret_cast<const bf16x8*>(&Ts[c*136 + r0]);
            }
        }
    }
}

// ---------------- Flash attention (R11 config): unpaired 128-row q-tiles,
// swapped QK^T, K/V via global_load_lds, hoisted LDS offsets, 3 blocks/CU.
__global__ __launch_bounds__(256, 3)
void attn_kernel(const short* __restrict__ qb, const short* __restrict__ kb,
                 const short* __restrict__ vtb, short* __restrict__ yb)
{
    __shared__ short Ks[2][64*64];   // [kv][d] bf16, SWZA chunk swizzle
    __shared__ short Vt[2][64*64];   // [d][kv] bf16, SWZA chunk swizzle
    __shared__ short Ps[4][32*64];   // per-wave P [qloc][kv] bf16, SWZA

    const int bh = blockIdx.x;            // 0..63 : id%8==bh%8 -> same-head blocks share XCD
    const int qt = 15 - blockIdx.y;       // descending: longest blocks dispatch first
    const int b_ = bh >> 4, h = bh & 15;
    const short* qp  = qb  + (size_t)bh*TT*HD;
    const short* kp  = kb  + (size_t)bh*TT*HD;
    const short* vtp = vtb + (size_t)bh*HD*TT;   // [d][T]
    const int t = threadIdx.x, wid = t >> 6, lane = t & 63;
    const int l15 = lane & 15, lh = lane >> 4;

    // ---- hoisted LDS byte offsets (static-indexed arrays -> register-resident)
    int kvoffB[8];   // [ks*4+i] : K-frag / V-frag / P-read offsets
#pragma unroll
    for (int ks=0;ks<2;ks++)
#pragma unroll
      for (int i=0;i<4;i++){
        int row = i*16 + l15;
        kvoffB[ks*4+i] = ((row*64 + ks*32 + lh*8) ^ SWZA(row)) * 2;
      }
    int pwB[8];      // [m*4+f] : P-write offsets (uint2)
#pragma unroll
    for (int m=0;m<2;m++){
        int qloc = m*16 + l15;
#pragma unroll
        for (int f=0;f<4;f++)
            pwB[m*4+f] = ((qloc*64 + f*16 + lh*4) ^ SWZA(qloc)) * 2;
    }
    char* KsB = (char*)&Ks[0][0];
    char* VtB = (char*)&Vt[0][0];
    char* PsB = (char*)&Ps[wid][0];

    // staging map: u = (wid*2+i)*64 + lane; row = u>>3, chunk = u&7 (16B chunks)
    const int su0 = (wid*2+0)*64 + lane;
    const int su1 = (wid*2+1)*64 + lane;
    const int sr0 = su0 >> 3, sc0 = (su0 & 7) ^ (SWZA(su0 >> 3) >> 3);
    const int sr1 = su1 >> 3, sc1 = (su1 & 7) ^ (SWZA(su1 >> 3) >> 3);

    // running global pointers (advance after each staged tile)
    const short* kg0 = kp  + (size_t)sr0*HD + sc0*8;
    const short* kg1 = kp  + (size_t)sr1*HD + sc1*8;
    const short* vg0 = vtp + (size_t)sr0*TT + sc0*8;
    const short* vg1 = vtp + (size_t)sr1*TT + sc1*8;

    const bf16x8 ones = { 0x3F80,0x3F80,0x3F80,0x3F80,0x3F80,0x3F80,0x3F80,0x3F80 };

    auto stageN = [&](int buf){
        ASYNC16(kg0, &Ks[buf][(wid*2+0)*512]);
        ASYNC16(kg1, &Ks[buf][(wid*2+1)*512]);
        ASYNC16(vg0, &Vt[buf][(wid*2+0)*512]);
        ASYNC16(vg1, &Vt[buf][(wid*2+1)*512]);
        kg0 += 64*HD; kg1 += 64*HD; vg0 += 64; vg1 += 64;
    };

    const int wq0 = qt*128 + wid*32;      // this wave's first q row

    bf16x8 qf[2][2];
#pragma unroll
    for (int m=0;m<2;m++)
#pragma unroll
      for (int ks=0;ks<2;ks++)
        qf[m][ks] = *reinterpret_cast<const bf16x8*>(
            &qp[(size_t)(wq0 + m*16 + l15)*HD + ks*32 + lh*8]);

    f32x4 po[2][4];
    f32x4 pden[2];
#pragma unroll
    for (int m=0;m<2;m++){
        pden[m] = (f32x4)0.f;
#pragma unroll
        for (int n=0;n<4;n++) po[m][n] = (f32x4)0.f;
    }

    const int ntk = 2*(qt + 1);           // always even

    stageN(0);
    __syncthreads();   // implicit vmcnt(0) drain before barrier

    for (int kt = 0; kt < ntk; ){
#pragma unroll
        for (int cur = 0; cur < 2; cur++, kt++){    // cur is compile-time after unroll
            const int kv0 = kt*64;
            if (kt+1 < ntk) stageN(cur ^ 1);        // fly during compute

            if (kv0 <= wq0 + 31){     // wave-uniform causal activity test
                // S^T = K Q^T : per lane q = l15 (const), kv = f*16 + lh*4 + r
                f32x4 s[2][4];
#pragma unroll
                for (int m=0;m<2;m++)
#pragma unroll
                  for (int f=0;f<4;f++) s[m][f] = (f32x4)0.f;
                __builtin_amdgcn_s_setprio(1);
#pragma unroll
                for (int ks=0;ks<2;ks++){
#pragma unroll
                    for (int f=0;f<4;f++){
                        bf16x8 kf = *reinterpret_cast<const bf16x8*>(
                            KsB + cur*8192 + kvoffB[ks*4+f]);
                        s[0][f] = MFMA(kf, qf[0][ks], s[0][f]);
                        s[1][f] = MFMA(kf, qf[1][ks], s[1][f]);
                    }
                }
                __builtin_amdgcn_s_setprio(0);
                // causal mask (straddling tiles only): q is per-lane scalar
#pragma unroll
                for (int m=0;m<2;m++){
                    if (kv0 + 63 > wq0 + m*16){
                        int qm = wq0 + m*16 + l15;
#pragma unroll
                        for (int f=0;f<4;f++)
#pragma unroll
                          for (int r=0;r<4;r++){
                            int kv = kv0 + f*16 + lh*4 + r;
                            if (kv > qm) s[m][f][r] = -1e30f;
                          }
                    }
                }
                // P = exp2(S'); pack via v_cvt_pk_bf16_f32; one b64 LDS write per f
#pragma unroll
                for (int m=0;m<2;m++){
#pragma unroll
                    for (int f=0;f<4;f++){
                        uint2 pk;
                        pk.x = cvtpk(exp2f(s[m][f][0]), exp2f(s[m][f][1]));
                        pk.y = cvtpk(exp2f(s[m][f][2]), exp2f(s[m][f][3]));
                        *reinterpret_cast<uint2*>(PsB + pwB[m*4+f]) = pk;
                    }
                }
                // O += P V ; den += P * 1  (ones-column via constant B-fragment)
                __builtin_amdgcn_s_setprio(1);
#pragma unroll
                for (int k2=0;k2<2;k2++){
                    bf16x8 pa[2];
#pragma unroll
                    for (int m=0;m<2;m++)
                        pa[m] = *reinterpret_cast<const bf16x8*>(PsB + kvoffB[k2*4+m]);
                    pden[0] = MFMA(pa[0], ones, pden[0]);
                    pden[1] = MFMA(pa[1], ones, pden[1]);
#pragma unroll
                    for (int n=0;n<4;n++){
                        bf16x8 vf = *reinterpret_cast<const bf16x8*>(
                            VtB + cur*8192 + kvoffB[k2*4+n]);
                        po[0][n] = MFMA(pa[0], vf, po[0][n]);
                        po[1][n] = MFMA(pa[1], vf, po[1][n]);
                    }
                }
                __builtin_amdgcn_s_setprio(0);
            }

            __syncthreads();   // drains staged loads (vmcnt) + publishes next buffer
        }
    }

    // epilogue -> y [B,T,C] bf16
#pragma unroll
    for (int m=0;m<2;m++){
        float rcp[4];
#pragma unroll
        for (int r=0;r<4;r++) rcp[r] = 1.f / pden[m][r];
#pragma unroll
        for (int n=0;n<4;n++)
#pragma unroll
          for (int r=0;r<4;r++){
            int q = wq0 + m*16 + lh*4 + r;
            int dd = n*16 + l15;
            yb[(size_t)(b_*TT + q)*CC + h*HD + dd] = f2bf(po[m][n][r] * rcp[r]);
          }
    }
}

// ---------------- Output projection (bf16): y [8192,1024] @ wpT^T + bias -> fp32 out
__global__ __launch_bounds__(256, 2)
void proj_gemm(const short* __restrict__ y, const short* __restrict__ wpT,
               const float* __restrict__ bias, float* __restrict__ out)
{
    __shared__ short As[128*64];
    __shared__ short Bs[128*64];
    const int bid = blockIdx.x;
    const int swz = (bid & 7) * 64 + (bid >> 3);   // 512 blocks
    const int bm = swz >> 3, bn = swz & 7;
    const int m0 = bm*128, n0 = bn*128;
    const int t  = threadIdx.x;
    const int wid = t >> 6, lane = t & 63;
    const int wr = wid >> 1, wc = wid & 1;
    const int l15 = lane & 15, lh = lane >> 4;

    f32x4 acc[4][4];
#pragma unroll
    for (int i=0;i<4;i++)
#pragma unroll
      for (int j=0;j<4;j++) acc[i][j] = (f32x4)0.f;

    for (int k0 = 0; k0 < CC; k0 += 64) {
        __syncthreads();
#pragma unroll
        for (int i=0;i<4;i++){
            int u   = (wid*4 + i)*64 + lane;
            int row = u >> 3, c = u & 7;
            int cs  = c ^ (row & 7);
            ASYNC16(&y[(size_t)(m0+row)*CC + k0 + cs*8],   &As[(wid*4+i)*512]);
            ASYNC16(&wpT[(size_t)(n0+row)*CC + k0 + cs*8], &Bs[(wid*4+i)*512]);
        }
        __syncthreads();
#pragma unroll
        for (int ks=0;ks<2;ks++){
            bf16x8 a[4], b[4];
#pragma unroll
            for (int m=0;m<4;m++){
                int row = wr*64 + m*16 + l15;
                a[m] = *reinterpret_cast<const bf16x8*>(&As[row*64 + (((ks<<2)|lh) ^ (row&7))*8]);
            }
#pragma unroll
            for (int n=0;n<4;n++){
                int col = wc*64 + n*16 + l15;
                b[n] = *reinterpret_cast<const bf16x8*>(&Bs[col*64 + (((ks<<2)|lh) ^ (col&7))*8]);
            }
#pragma unroll
            for (int m=0;m<4;m++)
#pragma unroll
              for (int n=0;n<4;n++)
                acc[m][n] = MFMA(a[m], b[n], acc[m][n]);
        }
    }

#pragma unroll
    for (int n=0;n<4;n++){
        int col = n0 + wc*64 + n*16 + l15;
        float bv = bias[col];
#pragma unroll
        for (int m=0;m<4;m++)
#pragma unroll
          for (int r=0;r<4;r++){
            int row = m0 + wr*64 + m*16 + lh*4 + r;
            out[(size_t)row*CC + col] = acc[m][n][r] + bv;
          }
    }
}

extern "C" void kernel_launch(void* const* d_in, const int* in_sizes, int n_in,
                              void* d_out, int out_size, void* d_ws, size_t ws_size,
                              hipStream_t stream) {
    const float* x      = (const float*)d_in[0];
    const float* w_attn = (const float*)d_in[1];
    const float* b_attn = (const float*)d_in[2];
    const float* w_proj = (const float*)d_in[3];
    const float* b_proj = (const float*)d_in[4];
    float* out = (float*)d_out;

    const size_t S = (size_t)BB*TT*CC;   // 8.4M elems
    short* qb  = (short*)d_ws;           // bf16 [B,H,T,HD]
    short* kb  = qb + S;
    short* vtb = kb + S;                 // bf16 [B,H,HD,T]  (V written transposed by qkv)
    short* yx  = vtb + S;                // x-bf16 during prepass+qkv; y-bf16 after attn
    short* wT  = yx + S;                 // bf16 [3072][1024]
    short* wpT = wT + (size_t)NQ*CC;     // bf16 [1024][1024]

    convert_x<<<dim3(S/(256*8)), 256, 0, stream>>>(x, yx);
    transpose_w<<<dim3(CC/64, NQ/64), 256, 0, stream>>>(w_attn, wT, NQ);
    transpose_w<<<dim3(CC/64, CC/64), 256, 0, stream>>>(w_proj, wpT, CC);
    qkv_gemm<<<dim3((BB*TT/128)*(NQ/128)), 256, 0, stream>>>(yx, wT, b_attn, qb, kb, vtb);
    attn_kernel<<<dim3(BB*HH, TT/128), 256, 0, stream>>>(qb, kb, vtb, yx);
    proj_gemm<<<dim3((BB*TT/128)*(CC/128)), 256, 0, stream>>>(yx, wpT, b_proj, out);
}

// Round 17
// 170.390 us; speedup vs baseline: 1.0352x; 1.0022x over previous
//
#include <hip/hip_runtime.h>
#include <hip/hip_bf16.h>

#define BB 4
#define TT 2048
#define CC 1024
#define HH 16
#define HD 64
#define NQ (3*CC)
// 1/sqrt(64) * log2(e): attention done in exp2 domain
#define QSCALE 0.18033688011112042f

typedef __attribute__((ext_vector_type(8))) short bf16x8;
typedef __attribute__((ext_vector_type(4))) short short4_t;
typedef __attribute__((ext_vector_type(4))) float f32x4;

#define MFMA(a,b,c) __builtin_amdgcn_mfma_f32_16x16x32_bf16(a,b,c,0,0,0)

// async global->LDS, 16B per lane; LDS dest is wave-uniform base + lane*16
#define ASYNC16(gsrc, ldst) \
  __builtin_amdgcn_global_load_lds((const __attribute__((address_space(1))) void*)(gsrc), \
                                   (__attribute__((address_space(3))) void*)(ldst), 16, 0, 0)

// row-swizzle for 64-short-stride LDS tiles (16B-chunk granularity)
#define SWZA(row) (((((row) & 7) + (((row) >> 3) & 3)) & 7) << 3)

static __device__ __forceinline__ short f2bf(float f){
    union { float f; unsigned u; } v; v.f = f;
    unsigned r = v.u + 0x7FFFu + ((v.u >> 16) & 1u);   // RNE
    return (short)(r >> 16);
}
// packed f32x2 -> bf16x2 (RNE), single HW instruction
static __device__ __forceinline__ unsigned cvtpk(float a, float b){
    unsigned r;
    asm("v_cvt_pk_bf16_f32 %0, %1, %2" : "=v"(r) : "v"(a), "v"(b));
    return r;
}

// ---------------- prepass: x fp32 -> bf16 via v_cvt_pk_bf16_f32 (4 VALU / 8 elems)
__global__ __launch_bounds__(256)
void convert_x(const float* __restrict__ x, short* __restrict__ xb)
{
    int i = (blockIdx.x * 256 + threadIdx.x) * 8;
    float4 a = *reinterpret_cast<const float4*>(&x[i]);
    float4 b = *reinterpret_cast<const float4*>(&x[i+4]);
    uint4 o = { cvtpk(a.x, a.y), cvtpk(a.z, a.w),
                cvtpk(b.x, b.y), cvtpk(b.z, b.w) };
    *reinterpret_cast<uint4*>(&xb[i]) = o;
}

// ---------------- prepass: w fp32 [K=1024][N] -> wT bf16 [N][1024]
__global__ __launch_bounds__(256)
void transpose_w(const float* __restrict__ w, short* __restrict__ wT, int N)
{
    __shared__ short sm[64*72];
    const int kt0 = blockIdx.x * 64;
    const int nt0 = blockIdx.y * 64;
    const int t = threadIdx.x;
    const int r  = t >> 4;
    const int c4 = (t & 15) * 4;
#pragma unroll
    for (int it = 0; it < 4; it++){
        int k = r + it*16;
        float4 v = *reinterpret_cast<const float4*>(&w[(size_t)(kt0 + k)*N + nt0 + c4]);
        sm[(c4+0)*72 + k] = f2bf(v.x);
        sm[(c4+1)*72 + k] = f2bf(v.y);
        sm[(c4+2)*72 + k] = f2bf(v.z);
        sm[(c4+3)*72 + k] = f2bf(v.w);
    }
    __syncthreads();
    const int nl = t >> 2;
    const int kc = (t & 3) * 16;
    bf16x8 o0 = *reinterpret_cast<const bf16x8*>(&sm[nl*72 + kc]);
    bf16x8 o1 = *reinterpret_cast<const bf16x8*>(&sm[nl*72 + kc + 8]);
    short* dst = &wT[(size_t)(nt0 + nl)*CC + kt0 + kc];
    *reinterpret_cast<bf16x8*>(dst)     = o0;
    *reinterpret_cast<bf16x8*>(dst + 8) = o1;
}

// ---------------- QKV GEMM (bf16): xb [8192,1024] @ wT^T -> q/k bf16 [B,H,T,HD],
// v written TRANSPOSED to vtb [B,H,HD,T] via LDS bounce (v-blocks: bn 16..23).
__global__ __launch_bounds__(256, 2)
void qkv_gemm(const short* __restrict__ xb, const short* __restrict__ wT,
              const float* __restrict__ bias,
              short* __restrict__ qb, short* __restrict__ kb, short* __restrict__ vtb)
{
    __shared__ short smem[128*136];      // As+Bs (16384) and epilogue Ts (17408)
    short* As = smem;                    // [128*64]
    short* Bs = smem + 8192;             // [128*64]
    const int bid = blockIdx.x;
    const int swz = (bid & 7) * 192 + (bid >> 3);   // 1536 blocks, bijective XCD swizzle
    const int bm = swz / (NQ/128);
    const int bn = swz % (NQ/128);
    const int m0 = bm*128, n0 = bn*128;
    const int t  = threadIdx.x;
    const int wid = t >> 6, lane = t & 63;
    const int wr = wid >> 1, wc = wid & 1;
    const int l15 = lane & 15, lh = lane >> 4;

    f32x4 acc[4][4];
#pragma unroll
    for (int i=0;i<4;i++)
#pragma unroll
      for (int j=0;j<4;j++) acc[i][j] = (f32x4)0.f;

    for (int k0 = 0; k0 < CC; k0 += 64) {
        __syncthreads();
#pragma unroll
        for (int i=0;i<4;i++){
            int u   = (wid*4 + i)*64 + lane;
            int row = u >> 3, c = u & 7;
            int cs  = c ^ (row & 7);      // inverse-swizzled source chunk
            ASYNC16(&xb[(size_t)(m0+row)*CC + k0 + cs*8], &As[(wid*4+i)*512]);
            ASYNC16(&wT[(size_t)(n0+row)*CC + k0 + cs*8], &Bs[(wid*4+i)*512]);
        }
        __syncthreads();
#pragma unroll
        for (int ks=0;ks<2;ks++){
            bf16x8 a[4], b[4];
#pragma unroll
            for (int m=0;m<4;m++){
                int row = wr*64 + m*16 + l15;
                a[m] = *reinterpret_cast<const bf16x8*>(&As[row*64 + (((ks<<2)|lh) ^ (row&7))*8]);
            }
#pragma unroll
            for (int n=0;n<4;n++){
                int col = wc*64 + n*16 + l15;
                b[n] = *reinterpret_cast<const bf16x8*>(&Bs[col*64 + (((ks<<2)|lh) ^ (col&7))*8]);
            }
#pragma unroll
            for (int m=0;m<4;m++)
#pragma unroll
              for (int n=0;n<4;n++)
                acc[m][n] = MFMA(a[m], b[n], acc[m][n]);
        }
    }

    if (n0 < 2*CC) {
        // q/k epilogue: scatter [B,H,T,HD]; fold exp2-domain scale into q
#pragma unroll
        for (int n=0;n<4;n++){
            int col = n0 + wc*64 + n*16 + l15;
            int sect = col >> 10;
            int cc = col & 1023;
            int h = cc >> 6, d = cc & 63;
            float bv = bias[col];
            short* dst = (sect==0) ? qb : kb;
            float mul = (sect==0) ? QSCALE : 1.f;
#pragma unroll
            for (int m=0;m<4;m++)
#pragma unroll
              for (int r=0;r<4;r++){
                int row = m0 + wr*64 + m*16 + lh*4 + r;
                int b_ = row >> 11, tt_ = row & (TT-1);
                float v = (acc[m][n][r] + bv) * mul;
                dst[((size_t)(b_*HH + h)*TT + tt_)*HD + d] = f2bf(v);
              }
        }
    } else {
        // v epilogue: transpose 128x128 tile via LDS -> vtb [bh][d][T] coalesced
        __syncthreads();                 // all waves done reading As/Bs
        short* Ts = smem;                // [128 cols][136]
#pragma unroll
        for (int n=0;n<4;n++){
            int colL = wc*64 + n*16 + l15;
            float bv = bias[n0 + colL];
#pragma unroll
            for (int m=0;m<4;m++){
                int rowL = wr*64 + m*16 + lh*4;
                short4_t pk = { f2bf(acc[m][n][0]+bv), f2bf(acc[m][n][1]+bv),
                                f2bf(acc[m][n][2]+bv), f2bf(acc[m][n][3]+bv) };
                *reinterpret_cast<short4_t*>(&Ts[colL*136 + rowL]) = pk;
            }
        }
        __syncthreads();
        const int b_ = m0 >> 11, t0 = m0 & (TT-1);
        const int cc0 = n0 - 2*CC;
#pragma unroll
        for (int pass=0;pass<2;pass++){
            int c = (t >> 2) + pass*64;
            int vcol = cc0 + c;
            short* dst = vtb + ((size_t)(b_*HH + (vcol>>6))*HD + (vcol&63))*TT + t0;
#pragma unroll
            for (int it=0;it<4;it++){
                int r0 = (t & 3)*8 + it*32;
                *reinterpret_cast<bf16x8*>(&dst[r0]) =
                    *reinterpret_cast<const bf16x8*>(&Ts[c*136 + r0]);
            }
        }
    }
}

// ---------------- Flash attention (R11 config): unpaired 128-row q-tiles,
// swapped QK^T, K/V via global_load_lds, hoisted LDS offsets, 3 blocks/CU.
__global__ __launch_bounds__(256, 3)
void attn_kernel(const short* __restrict__ qb, const short* __restrict__ kb,
                 const short* __restrict__ vtb, short* __restrict__ yb)
{
    __shared__ short Ks[2][64*64];   // [kv][d] bf16, SWZA chunk swizzle
    __shared__ short Vt[2][64*64];   // [d][kv] bf16, SWZA chunk swizzle
    __shared__ short Ps[4][32*64];   // per-wave P [qloc][kv] bf16, SWZA

    const int bh = blockIdx.x;            // 0..63 : id%8==bh%8 -> same-head blocks share XCD
    const int qt = 15 - blockIdx.y;       // descending: longest blocks dispatch first
    const int b_ = bh >> 4, h = bh & 15;
    const short* qp  = qb  + (size_t)bh*TT*HD;
    const short* kp  = kb  + (size_t)bh*TT*HD;
    const short* vtp = vtb + (size_t)bh*HD*TT;   // [d][T]
    const int t = threadIdx.x, wid = t >> 6, lane = t & 63;
    const int l15 = lane & 15, lh = lane >> 4;

    // ---- hoisted LDS byte offsets (static-indexed arrays -> register-resident)
    int kvoffB[8];   // [ks*4+i] : K-frag / V-frag / P-read offsets
#pragma unroll
    for (int ks=0;ks<2;ks++)
#pragma unroll
      for (int i=0;i<4;i++){
        int row = i*16 + l15;
        kvoffB[ks*4+i] = ((row*64 + ks*32 + lh*8) ^ SWZA(row)) * 2;
      }
    int pwB[8];      // [m*4+f] : P-write offsets (uint2)
#pragma unroll
    for (int m=0;m<2;m++){
        int qloc = m*16 + l15;
#pragma unroll
        for (int f=0;f<4;f++)
            pwB[m*4+f] = ((qloc*64 + f*16 + lh*4) ^ SWZA(qloc)) * 2;
    }
    char* KsB = (char*)&Ks[0][0];
    char* VtB = (char*)&Vt[0][0];
    char* PsB = (char*)&Ps[wid][0];

    // staging map: u = (wid*2+i)*64 + lane; row = u>>3, chunk = u&7 (16B chunks)
    const int su0 = (wid*2+0)*64 + lane;
    const int su1 = (wid*2+1)*64 + lane;
    const int sr0 = su0 >> 3, sc0 = (su0 & 7) ^ (SWZA(su0 >> 3) >> 3);
    const int sr1 = su1 >> 3, sc1 = (su1 & 7) ^ (SWZA(su1 >> 3) >> 3);

    // running global pointers (advance after each staged tile)
    const short* kg0 = kp  + (size_t)sr0*HD + sc0*8;
    const short* kg1 = kp  + (size_t)sr1*HD + sc1*8;
    const short* vg0 = vtp + (size_t)sr0*TT + sc0*8;
    const short* vg1 = vtp + (size_t)sr1*TT + sc1*8;

    const bf16x8 ones = { 0x3F80,0x3F80,0x3F80,0x3F80,0x3F80,0x3F80,0x3F80,0x3F80 };

    auto stageN = [&](int buf){
        ASYNC16(kg0, &Ks[buf][(wid*2+0)*512]);
        ASYNC16(kg1, &Ks[buf][(wid*2+1)*512]);
        ASYNC16(vg0, &Vt[buf][(wid*2+0)*512]);
        ASYNC16(vg1, &Vt[buf][(wid*2+1)*512]);
        kg0 += 64*HD; kg1 += 64*HD; vg0 += 64; vg1 += 64;
    };

    const int wq0 = qt*128 + wid*32;      // this wave's first q row

    bf16x8 qf[2][2];
#pragma unroll
    for (int m=0;m<2;m++)
#pragma unroll
      for (int ks=0;ks<2;ks++)
        qf[m][ks] = *reinterpret_cast<const bf16x8*>(
            &qp[(size_t)(wq0 + m*16 + l15)*HD + ks*32 + lh*8]);

    f32x4 po[2][4];
    f32x4 pden[2];
#pragma unroll
    for (int m=0;m<2;m++){
        pden[m] = (f32x4)0.f;
#pragma unroll
        for (int n=0;n<4;n++) po[m][n] = (f32x4)0.f;
    }

    const int ntk = 2*(qt + 1);           // always even

    stageN(0);
    __syncthreads();   // implicit vmcnt(0) drain before barrier

    for (int kt = 0; kt < ntk; ){
#pragma unroll
        for (int cur = 0; cur < 2; cur++, kt++){    // cur is compile-time after unroll
            const int kv0 = kt*64;
            if (kt+1 < ntk) stageN(cur ^ 1);        // fly during compute

            if (kv0 <= wq0 + 31){     // wave-uniform causal activity test
                // S^T = K Q^T : per lane q = l15 (const), kv = f*16 + lh*4 + r
                f32x4 s[2][4];
#pragma unroll
                for (int m=0;m<2;m++)
#pragma unroll
                  for (int f=0;f<4;f++) s[m][f] = (f32x4)0.f;
                __builtin_amdgcn_s_setprio(1);
#pragma unroll
                for (int ks=0;ks<2;ks++){
#pragma unroll
                    for (int f=0;f<4;f++){
                        bf16x8 kf = *reinterpret_cast<const bf16x8*>(
                            KsB + cur*8192 + kvoffB[ks*4+f]);
                        s[0][f] = MFMA(kf, qf[0][ks], s[0][f]);
                        s[1][f] = MFMA(kf, qf[1][ks], s[1][f]);
                    }
                }
                __builtin_amdgcn_s_setprio(0);
                // causal mask (straddling tiles only): q is per-lane scalar
#pragma unroll
                for (int m=0;m<2;m++){
                    if (kv0 + 63 > wq0 + m*16){
                        int qm = wq0 + m*16 + l15;
#pragma unroll
                        for (int f=0;f<4;f++)
#pragma unroll
                          for (int r=0;r<4;r++){
                            int kv = kv0 + f*16 + lh*4 + r;
                            if (kv > qm) s[m][f][r] = -1e30f;
                          }
                    }
                }
                // P = exp2(S'); pack via v_cvt_pk_bf16_f32; one b64 LDS write per f
#pragma unroll
                for (int m=0;m<2;m++){
#pragma unroll
                    for (int f=0;f<4;f++){
                        uint2 pk;
                        pk.x = cvtpk(exp2f(s[m][f][0]), exp2f(s[m][f][1]));
                        pk.y = cvtpk(exp2f(s[m][f][2]), exp2f(s[m][f][3]));
                        *reinterpret_cast<uint2*>(PsB + pwB[m*4+f]) = pk;
                    }
                }
                // O += P V ; den += P * 1  (ones-column via constant B-fragment)
                __builtin_amdgcn_s_setprio(1);
#pragma unroll
                for (int k2=0;k2<2;k2++){
                    bf16x8 pa[2];
#pragma unroll
                    for (int m=0;m<2;m++)
                        pa[m] = *reinterpret_cast<const bf16x8*>(PsB + kvoffB[k2*4+m]);
                    pden[0] = MFMA(pa[0], ones, pden[0]);
                    pden[1] = MFMA(pa[1], ones, pden[1]);
#pragma unroll
                    for (int n=0;n<4;n++){
                        bf16x8 vf = *reinterpret_cast<const bf16x8*>(
                            VtB + cur*8192 + kvoffB[k2*4+n]);
                        po[0][n] = MFMA(pa[0], vf, po[0][n]);
                        po[1][n] = MFMA(pa[1], vf, po[1][n]);
                    }
                }
                __builtin_amdgcn_s_setprio(0);
            }

            __syncthreads();   // drains staged loads (vmcnt) + publishes next buffer
        }
    }

    // epilogue -> y [B,T,C] bf16
#pragma unroll
    for (int m=0;m<2;m++){
        float rcp[4];
#pragma unroll
        for (int r=0;r<4;r++) rcp[r] = 1.f / pden[m][r];
#pragma unroll
        for (int n=0;n<4;n++)
#pragma unroll
          for (int r=0;r<4;r++){
            int q = wq0 + m*16 + lh*4 + r;
            int dd = n*16 + l15;
            yb[(size_t)(b_*TT + q)*CC + h*HD + dd] = f2bf(po[m][n][r] * rcp[r]);
          }
    }
}

// ---------------- Output projection (bf16): y [8192,1024] @ wpT^T + bias -> fp32 out
__global__ __launch_bounds__(256, 2)
void proj_gemm(const short* __restrict__ y, const short* __restrict__ wpT,
               const float* __restrict__ bias, float* __restrict__ out)
{
    __shared__ short As[128*64];
    __shared__ short Bs[128*64];
    const int bid = blockIdx.x;
    const int swz = (bid & 7) * 64 + (bid >> 3);   // 512 blocks
    const int bm = swz >> 3, bn = swz & 7;
    const int m0 = bm*128, n0 = bn*128;
    const int t  = threadIdx.x;
    const int wid = t >> 6, lane = t & 63;
    const int wr = wid >> 1, wc = wid & 1;
    const int l15 = lane & 15, lh = lane >> 4;

    f32x4 acc[4][4];
#pragma unroll
    for (int i=0;i<4;i++)
#pragma unroll
      for (int j=0;j<4;j++) acc[i][j] = (f32x4)0.f;

    for (int k0 = 0; k0 < CC; k0 += 64) {
        __syncthreads();
#pragma unroll
        for (int i=0;i<4;i++){
            int u   = (wid*4 + i)*64 + lane;
            int row = u >> 3, c = u & 7;
            int cs  = c ^ (row & 7);
            ASYNC16(&y[(size_t)(m0+row)*CC + k0 + cs*8],   &As[(wid*4+i)*512]);
            ASYNC16(&wpT[(size_t)(n0+row)*CC + k0 + cs*8], &Bs[(wid*4+i)*512]);
        }
        __syncthreads();
#pragma unroll
        for (int ks=0;ks<2;ks++){
            bf16x8 a[4], b[4];
#pragma unroll
            for (int m=0;m<4;m++){
                int row = wr*64 + m*16 + l15;
                a[m] = *reinterpret_cast<const bf16x8*>(&As[row*64 + (((ks<<2)|lh) ^ (row&7))*8]);
            }
#pragma unroll
            for (int n=0;n<4;n++){
                int col = wc*64 + n*16 + l15;
                b[n] = *reinterpret_cast<const bf16x8*>(&Bs[col*64 + (((ks<<2)|lh) ^ (col&7))*8]);
            }
#pragma unroll
            for (int m=0;m<4;m++)
#pragma unroll
              for (int n=0;n<4;n++)
                acc[m][n] = MFMA(a[m], b[n], acc[m][n]);
        }
    }

#pragma unroll
    for (int n=0;n<4;n++){
        int col = n0 + wc*64 + n*16 + l15;
        float bv = bias[col];
#pragma unroll
        for (int m=0;m<4;m++)
#pragma unroll
          for (int r=0;r<4;r++){
            int row = m0 + wr*64 + m*16 + lh*4 + r;
            out[(size_t)row*CC + col] = acc[m][n][r] + bv;
          }
    }
}

extern "C" void kernel_launch(void* const* d_in, const int* in_sizes, int n_in,
                              void* d_out, int out_size, void* d_ws, size_t ws_size,
                              hipStream_t stream) {
    const float* x      = (const float*)d_in[0];
    const float* w_attn = (const float*)d_in[1];
    const float* b_attn = (const float*)d_in[2];
    const float* w_proj = (const float*)d_in[3];
    const float* b_proj = (const float*)d_in[4];
    float* out = (float*)d_out;

    const size_t S = (size_t)BB*TT*CC;   // 8.4M elems
    short* qb  = (short*)d_ws;           // bf16 [B,H,T,HD]
    short* kb  = qb + S;
    short* vtb = kb + S;                 // bf16 [B,H,HD,T]  (V written transposed by qkv)
    short* yx  = vtb + S;                // x-bf16 during prepass+qkv; y-bf16 after attn
    short* wT  = yx + S;                 // bf16 [3072][1024]
    short* wpT = wT + (size_t)NQ*CC;     // bf16 [1024][1024]

    convert_x<<<dim3(S/(256*8)), 256, 0, stream>>>(x, yx);
    transpose_w<<<dim3(CC/64, NQ/64), 256, 0, stream>>>(w_attn, wT, NQ);
    transpose_w<<<dim3(CC/64, CC/64), 256, 0, stream>>>(w_proj, wpT, CC);
    qkv_gemm<<<dim3((BB*TT/128)*(NQ/128)), 256, 0, stream>>>(yx, wT, b_attn, qb, kb, vtb);
    attn_kernel<<<dim3(BB*HH, TT/128), 256, 0, stream>>>(qb, kb, vtb, yx);
    proj_gemm<<<dim3((BB*TT/128)*(CC/128)), 256, 0, stream>>>(yx, wpT, b_proj, out);
}